// Round 5
// baseline (1991.094 us; speedup 1.0000x reference)
//
#include <hip/hip_runtime.h>

// SNN forward, xs-path only. Spike layouts zero-halo padded (N,H+2,W+2,T,C), T=40.
// Convs 2-7: MFMA 16x16x32 bf16, EXACT 3-way bf16 weight split, 2-phase pipelined
// K-loop: global_load_lds (pre-swizzled source) + double-buffered LDS + raw
// s_barrier with one vmcnt(0) per chunk (loads issued before MFMAs -> hidden).

constexpr int NT = 40;

typedef __attribute__((ext_vector_type(8))) short s16x8;
typedef __attribute__((ext_vector_type(4))) float f32x4;

__device__ __forceinline__ float bf2f(unsigned short u) {
    return __uint_as_float(((unsigned)u) << 16);
}

#define GLOAD16(gp, lp) __builtin_amdgcn_global_load_lds(                      \
    (const __attribute__((address_space(1))) void*)(gp),                       \
    (__attribute__((address_space(3))) void*)(lp), 16, 0, 0)

// ---------------- weight transpose for conv1 ----------------
__global__ __launch_bounds__(256) void transpose_w(
    const float* __restrict__ w, float* __restrict__ wt, int CO, int R)
{
    __shared__ float tile[32][33];
    const int r0 = blockIdx.x * 32, c0 = blockIdx.y * 32;
    const int tx = threadIdx.x % 32, ty = threadIdx.x / 32;
#pragma unroll
    for (int k = 0; k < 4; k++) {
        const int co = c0 + ty + k * 8, r = r0 + tx;
        if (co < CO && r < R) tile[ty + k * 8][tx] = w[(size_t)co * R + r];
    }
    __syncthreads();
#pragma unroll
    for (int k = 0; k < 4; k++) {
        const int r = r0 + ty + k * 8, co = c0 + tx;
        if (r < R && co < CO) wt[(size_t)r * CO + co] = tile[tx][ty + k * 8];
    }
}

// ---------------- conv1: 3->128 @32x32 pad1, fp32 VALU, dense out ----------------
__global__ __launch_bounds__(320) void conv1_c(
    const float* __restrict__ in, const float* __restrict__ wt,
    const float* __restrict__ bias, float* __restrict__ out)
{
    __shared__ float xs_[27 * NT];
    __shared__ float wl[27 * 128];
    const int sp = blockIdx.x;
    const int ho = sp >> 5, wo = sp & 31;
    const int n = blockIdx.z;
    const int tid = threadIdx.x;
    const int tt = tid >> 5;
    const int cc = tid & 31;

    float4 acc[4];
#pragma unroll
    for (int j = 0; j < 4; j++) {
        const float bv = bias[cc * 4 + j];
        acc[j] = make_float4(bv, bv, bv, bv);
    }
    for (int u = tid; u < 270; u += 320) {
        const int r = u / 10, q = u % 10;
        const int cil = r / 9, k = r % 9;
        const int hi = ho + k / 3 - 1, wi = wo + k % 3 - 1;
        float4 v = make_float4(0.f, 0.f, 0.f, 0.f);
        if ((unsigned)hi < 32u && (unsigned)wi < 32u)
            v = *reinterpret_cast<const float4*>(
                in + ((size_t)((n * 3 + cil) * 1024 + hi * 32 + wi)) * NT + q * 4);
        *reinterpret_cast<float4*>(&xs_[r * NT + q * 4]) = v;
    }
    for (int u = tid; u < 864; u += 320) {
        const int r = u >> 5, j = u & 31;
        *reinterpret_cast<float4*>(&wl[r * 128 + j * 4]) =
            *reinterpret_cast<const float4*>(wt + r * 128 + j * 4);
    }
    __syncthreads();
#pragma unroll
    for (int r = 0; r < 27; ++r) {
        const float4 xv = *reinterpret_cast<const float4*>(&xs_[r * NT + tt * 4]);
        const float4 wv = *reinterpret_cast<const float4*>(&wl[r * 128 + cc * 4]);
        acc[0].x = fmaf(xv.x, wv.x, acc[0].x); acc[0].y = fmaf(xv.y, wv.x, acc[0].y);
        acc[0].z = fmaf(xv.z, wv.x, acc[0].z); acc[0].w = fmaf(xv.w, wv.x, acc[0].w);
        acc[1].x = fmaf(xv.x, wv.y, acc[1].x); acc[1].y = fmaf(xv.y, wv.y, acc[1].y);
        acc[1].z = fmaf(xv.z, wv.y, acc[1].z); acc[1].w = fmaf(xv.w, wv.y, acc[1].w);
        acc[2].x = fmaf(xv.x, wv.z, acc[2].x); acc[2].y = fmaf(xv.y, wv.z, acc[2].y);
        acc[2].z = fmaf(xv.z, wv.z, acc[2].z); acc[2].w = fmaf(xv.w, wv.z, acc[2].w);
        acc[3].x = fmaf(xv.x, wv.w, acc[3].x); acc[3].y = fmaf(xv.y, wv.w, acc[3].y);
        acc[3].z = fmaf(xv.z, wv.w, acc[3].z); acc[3].w = fmaf(xv.w, wv.w, acc[3].w);
    }
    const size_t base = (size_t)(n * 1024 + sp) * (NT * 128);
#pragma unroll
    for (int j = 0; j < 4; j++) {
        const int cb = cc * 4 + j;
        out[base + (tt * 4 + 0) * 128 + cb] = acc[j].x;
        out[base + (tt * 4 + 1) * 128 + cb] = acc[j].y;
        out[base + (tt * 4 + 2) * 128 + cb] = acc[j].z;
        out[base + (tt * 4 + 3) * 128 + cb] = acc[j].w;
    }
}

// ---------------- exact 3-way bf16 split: w[CO][CIN*9] -> {hi,mid,lo}[9][CO][CIN] ----------------
__global__ void split_w(const float* __restrict__ w,
                        unsigned short* __restrict__ hi, unsigned short* __restrict__ mid,
                        unsigned short* __restrict__ lo, int CO, int CIN_)
{
    const int idx = blockIdx.x * blockDim.x + threadIdx.x;
    if (idx >= CO * CIN_) return;
    const int co = idx / CIN_, ci = idx % CIN_;
    const float* src = w + ((size_t)co * CIN_ + ci) * 9;
#pragma unroll
    for (int k = 0; k < 9; ++k) {
        const float f = src[k];
        const unsigned u = __float_as_uint(f);
        const float fh = __uint_as_float(u & 0xFFFF0000u);
        const float r1 = f - fh;
        const unsigned u1 = __float_as_uint(r1);
        const float fm = __uint_as_float(u1 & 0xFFFF0000u);
        const float r2 = r1 - fm;
        const unsigned u2 = __float_as_uint(r2);
        const size_t dst = ((size_t)k * CO + co) * CIN_ + ci;
        hi[dst] = (unsigned short)(u >> 16);
        mid[dst] = (unsigned short)(u1 >> 16);
        lo[dst] = (unsigned short)(u2 >> 16);
    }
}

// ---------------- pipelined MFMA conv on padded spikes ----------------
// in: spikes (2, HP, WP, T, CIN) bf16, zero halo; out dense (2, HP-2, WP-2, T, COUT) fp32
// BM=64 rows x 2 images, BN=64 cols, 2x2 waves, K-chunk = 64 ci per kernel tap.
template<int CIN_SEG, int COUT, int HP, int WP, int NSPLIT>
__global__ __launch_bounds__(256, 2) void conv_p(
    const unsigned short* __restrict__ spk,
    const unsigned short* __restrict__ wlo, const unsigned short* __restrict__ wmid,
    const unsigned short* __restrict__ whi,
    const float* __restrict__ bias, float* __restrict__ out)
{
    constexpr int CIN = CIN_SEG * NSPLIT;
    constexpr int HO = HP - 2, WO = WP - 2;
    constexpr int MROW = WO * NT;
    constexpr int MTILES = (MROW + 63) / 64;
    constexpr int KC = CIN_SEG / 64;
    constexpr int NCHUNK = 9 * KC;
    constexpr int NX = HO * MTILES;
    constexpr int NY = COUT / 64;
    constexpr int NB = NX * NY * NSPLIT;
    static_assert(NB % 8 == 0, "grid must divide across 8 XCDs");
    constexpr int Q = NB / 8;
    constexpr int ASH = 2 * 64 * 64;            // A region: 8192 shorts
    constexpr int BUFSH = ASH + 3 * 64 * 64;    // + B region: 20480 shorts / buffer
    constexpr size_t SLAB = (size_t)2 * HO * WO * NT * COUT;

    extern __shared__ unsigned short smem_raw[];   // 2 * 20480 shorts = 80 KiB

    // XCD-chunked swizzle, z(split)-fastest then x then y
    const int g = blockIdx.x;
    const int orig = (g & 7) * Q + (g >> 3);
    const int split = orig % NSPLIT;
    const int x = (orig / NSPLIT) % NX;
    const int y = orig / (NSPLIT * NX);
    const int ho = x / MTILES;
    const int m0 = (x % MTILES) * 64;
    const int co0 = y * 64;

    const int tid = threadIdx.x;
    const int lane = tid & 63;
    const int wv = tid >> 6;
    const int wm = wv >> 1, wn = wv & 1;
    const int lr = lane >> 4, lc = lane & 15;
    // pre-swizzled per-lane source offset: row (lane>>3), 16B-block (lane&7)^((lane>>3)&7)
    const size_t laneoff = (size_t)(lane >> 3) * CIN + (size_t)((((lane & 7) ^ ((lane >> 3) & 7))) << 3);

    f32x4 acc[2][2][2];
#pragma unroll
    for (int img = 0; img < 2; ++img)
#pragma unroll
        for (int mf = 0; mf < 2; ++mf)
#pragma unroll
            for (int nf = 0; nf < 2; ++nf) {
                const float bv = (NSPLIT == 1 || split == 0)
                    ? bias[co0 + wn * 32 + nf * 16 + lc] : 0.f;
                acc[img][mf][nf] = {bv, bv, bv, bv};
            }

    auto stage = [&](int buf, int c) {
        const int kh = c / (3 * KC);
        const int rem = c - kh * 3 * KC;
        const int kw = rem / KC;
        const int kc = rem - kw * KC;
        const int ci0 = split * CIN_SEG + kc * 64;
        const int khw = kh * 3 + kw;
        unsigned short* lbase = smem_raw + (size_t)buf * BUFSH;
#pragma unroll
        for (int s = 0; s < 10; ++s) {
            const int slot = wv * 10 + s;           // 0-15: A (2 img), 16-39: B (3 splits)
            const unsigned short* gp;
            int lofs;
            if (slot < 16) {
                const int img = slot >> 3;
                const int r0 = (slot & 7) << 3;
                const size_t rowpos = (size_t)((img * HP + ho + kh) * WP) * NT
                                      + (size_t)(m0 + kw * NT + r0);
                gp = spk + rowpos * CIN + ci0 + laneoff;
                lofs = (img * 64 + r0) * 64;
            } else {
                const int si = slot - 16;
                const int sp_ = si >> 3;
                const int r0 = (si & 7) << 3;
                const unsigned short* wb = (sp_ == 0) ? wlo : ((sp_ == 1) ? wmid : whi);
                gp = wb + ((size_t)(khw * COUT + co0) + r0) * CIN + ci0 + laneoff;
                lofs = ASH + (sp_ * 64 + r0) * 64;
            }
            GLOAD16(gp, lbase + lofs);
        }
    };

    auto compute = [&](int buf) {
        const unsigned short* sb = smem_raw + (size_t)buf * BUFSH;
#pragma unroll
        for (int kcs = 0; kcs < 2; ++kcs) {
            const int c16 = kcs * 4 + lr;
            s16x8 af[2][2];
#pragma unroll
            for (int img = 0; img < 2; ++img)
#pragma unroll
                for (int mf = 0; mf < 2; ++mf) {
                    const int Ra = img * 64 + wm * 32 + mf * 16 + lc;
                    af[img][mf] = *(const s16x8*)&sb[Ra * 64 + ((c16 ^ (Ra & 7)) << 3)];
                }
#pragma unroll
            for (int s = 0; s < 3; ++s) {
#pragma unroll
                for (int nf = 0; nf < 2; ++nf) {
                    const int Rb = wn * 32 + nf * 16 + lc;
                    const s16x8 bq = *(const s16x8*)&sb[ASH + s * 4096 + Rb * 64 + ((c16 ^ (Rb & 7)) << 3)];
#pragma unroll
                    for (int img = 0; img < 2; ++img)
#pragma unroll
                        for (int mf = 0; mf < 2; ++mf)
                            acc[img][mf][nf] = __builtin_amdgcn_mfma_f32_16x16x32_bf16(
                                af[img][mf], bq, acc[img][mf][nf], 0, 0, 0);
                }
            }
        }
    };

    stage(0, 0);
    asm volatile("s_waitcnt vmcnt(0)" ::: "memory");
    __builtin_amdgcn_s_barrier();
    __builtin_amdgcn_sched_barrier(0);
    for (int c = 0; c < NCHUNK; ++c) {
        const int cur = c & 1;
        if (c + 1 < NCHUNK) stage(cur ^ 1, c + 1);   // loads in flight under MFMAs
        compute(cur);
        asm volatile("s_waitcnt vmcnt(0)" ::: "memory");
        __builtin_amdgcn_s_barrier();
        __builtin_amdgcn_sched_barrier(0);
    }

#pragma unroll
    for (int img = 0; img < 2; ++img) {
        float* outp = out + split * SLAB + ((size_t)(img * HO + ho) * WO * NT) * COUT;
#pragma unroll
        for (int mf = 0; mf < 2; ++mf) {
            const int mbase = m0 + wm * 32 + mf * 16;
            if (mbase >= MROW) continue;
#pragma unroll
            for (int nf = 0; nf < 2; ++nf) {
                const int col = co0 + wn * 32 + nf * 16 + lc;
#pragma unroll
                for (int j = 0; j < 4; ++j) {
                    const int m = mbase + lr * 4 + j;
                    outp[(size_t)m * COUT + col] = acc[img][mf][nf][j];
                }
            }
        }
    }
}

// ---------------- zero the 1-cell halo ring of a padded spike buffer ----------------
__global__ void halo_zero(unsigned short* __restrict__ buf, int HP, int WP, int TC)
{
    const int cell = blockIdx.x, n = blockIdx.y;
    int h, w;
    if (cell < WP)            { h = 0;       w = cell; }
    else if (cell < 2 * WP)   { h = HP - 1;  w = cell - WP; }
    else { const int s = cell - 2 * WP; h = 1 + (s >> 1); w = (s & 1) ? (WP - 1) : 0; }
    unsigned short* p = buf + (((size_t)(n * HP + h) * WP) + w) * TC;
    const s16x8 z = {0, 0, 0, 0, 0, 0, 0, 0};
    for (int i = threadIdx.x * 8; i < TC; i += blockDim.x * 8)
        *(s16x8*)(p + i) = z;
}

// ---------------- IF scan: fp32 dense conv-out -> bf16 spikes (padded or not) ----------------
__global__ void if_ci(const float* __restrict__ in, unsigned short* __restrict__ spk,
                      const float* __restrict__ thr, int C, int HO, int WO,
                      int HP, int WP, int off, int total)
{
    const int idx = blockIdx.x * blockDim.x + threadIdx.x;
    if (idx >= total) return;
    const int c = idx % C;
    const int sp = idx / C;
    const int wo = sp % WO;
    const int ho = (sp / WO) % HO;
    const int n = sp / (WO * HO);
    const float th = thr[c];
    const size_t ib = (size_t)sp * NT * C + c;
    const size_t ob = (((size_t)(n * HP + ho + off) * WP) + wo + off) * NT * C + c;
    float v = 0.f;
#pragma unroll
    for (int t = 0; t < NT; ++t) {
        v += in[ib + (size_t)t * C];
        const float s = (v >= th) ? 1.f : 0.f;
        v -= s * th;
        spk[ob + (size_t)t * C] = (s != 0.f) ? (unsigned short)0x3F80 : (unsigned short)0;
    }
}

// ---------------- pool 2x2 + IF, bf16 spikes in (padded) -> out (padded or not) ----------------
__global__ void pool_ci(const unsigned short* __restrict__ in, unsigned short* __restrict__ out,
                        const float* __restrict__ thr, int C, int HO, int WO,
                        int IHP, int IWP, int offi, int OHP, int OWP, int offo, int total)
{
    const int idx = blockIdx.x * blockDim.x + threadIdx.x;
    if (idx >= total) return;
    const int c = idx % C;
    const int sp = idx / C;
    const int wo = sp % WO;
    const int ho = (sp / WO) % HO;
    const int n = sp / (WO * HO);
    const float th = thr[c];
    const size_t i00 = (((size_t)(n * IHP + 2 * ho + offi) * IWP) + 2 * wo + offi) * NT * C + c;
    const size_t dW = (size_t)NT * C, dH = (size_t)IWP * NT * C;
    const size_t ob = (((size_t)(n * OHP + ho + offo) * OWP) + wo + offo) * NT * C + c;
    float v = 0.f;
#pragma unroll
    for (int t = 0; t < NT; ++t) {
        const size_t o = (size_t)t * C;
        const float a = bf2f(in[i00 + o]) + bf2f(in[i00 + dW + o]) +
                        bf2f(in[i00 + dH + o]) + bf2f(in[i00 + dH + dW + o]);
        v += a * 0.25f;
        const float s = (v >= th) ? 1.f : 0.f;
        v -= s * th;
        out[ob + o] = (s != 0.f) ? (unsigned short)0x3F80 : (unsigned short)0;
    }
}

// ---------------- conv7 4-way partial reduce + IF -> bf16 spikes (dense) ----------------
__global__ void reduce_if7(const float* __restrict__ part, unsigned short* __restrict__ out,
                           const float* __restrict__ thr, int total)
{
    const int idx = blockIdx.x * blockDim.x + threadIdx.x;
    if (idx >= total) return;
    const int c = idx & 1023;
    const size_t base = (size_t)(idx >> 10) * NT * 1024 + c;
    const size_t SL = 327680;
    const float th = thr[c];
    float v = 0.f;
#pragma unroll
    for (int t = 0; t < NT; ++t) {
        const size_t o = (size_t)t * 1024;
        const float x = part[base + o] + part[SL + base + o] +
                        part[2 * SL + base + o] + part[3 * SL + base + o];
        v += x;
        const float s = (v >= th) ? 1.f : 0.f;
        v -= s * th;
        out[base + o] = (s != 0.f) ? (unsigned short)0x3F80 : (unsigned short)0;
    }
}

// ---------------- classifier: bf16 spikes (N,T,1024) ----------------
__global__ __launch_bounds__(1024) void classifier_ci(
    const unsigned short* __restrict__ s, const float* __restrict__ wc,
    const float* __restrict__ bc, float* __restrict__ out)
{
    __shared__ float cnt[2][1024];
    const int c = threadIdx.x;
    for (int n = 0; n < 2; n++) {
        float sum = 0.f;
#pragma unroll
        for (int t = 0; t < NT; ++t) sum += bf2f(s[(size_t)(n * NT + t) * 1024 + c]);
        cnt[n][c] = sum;
    }
    __syncthreads();
    if (threadIdx.x < 20) {
        const int n = threadIdx.x / 10, o = threadIdx.x % 10;
        float a = 0.f;
        for (int k = 0; k < 1024; k++) a += cnt[n][k] * wc[o * 1024 + k];
        out[n * 10 + o] = a * (1.f / 40.f) + bc[o];
    }
}

extern "C" void kernel_launch(void* const* d_in, const int* in_sizes, int n_in,
                              void* d_out, int out_size, void* d_ws, size_t ws_size,
                              hipStream_t stream)
{
    const float* x   = (const float*)d_in[0];
    const float* w1  = (const float*)d_in[1];  const float* b1 = (const float*)d_in[2];
    const float* w2  = (const float*)d_in[3];  const float* b2 = (const float*)d_in[4];
    const float* w3  = (const float*)d_in[5];  const float* b3 = (const float*)d_in[6];
    const float* w4  = (const float*)d_in[7];  const float* b4 = (const float*)d_in[8];
    const float* w5  = (const float*)d_in[9];  const float* b5 = (const float*)d_in[10];
    const float* w6  = (const float*)d_in[11]; const float* b6 = (const float*)d_in[12];
    const float* w7  = (const float*)d_in[13]; const float* b7 = (const float*)d_in[14];
    const float* wc  = (const float*)d_in[15]; const float* bc = (const float*)d_in[16];
    const float* thr1 = (const float*)d_in[17];
    const float* thr2 = (const float*)d_in[18];
    const float* p1   = (const float*)d_in[19];
    const float* thr3 = (const float*)d_in[20];
    const float* thr4 = (const float*)d_in[21];
    const float* p2   = (const float*)d_in[22];
    const float* thr5 = (const float*)d_in[23];
    const float* thr6 = (const float*)d_in[24];
    const float* p3   = (const float*)d_in[25];
    const float* thr7 = (const float*)d_in[26];
    const float* p4   = (const float*)d_in[27];

    char* W0 = (char*)d_ws;
    float* OUT = (float*)W0;                                              // 40 MiB dense fp32
    unsigned short* WH   = (unsigned short*)(W0 + (40ull << 20));         // 9 MiB
    unsigned short* WMID = (unsigned short*)(W0 + (49ull << 20));         // 9 MiB
    unsigned short* WLO  = (unsigned short*)(W0 + (58ull << 20));         // 9 MiB
    unsigned short* R1   = (unsigned short*)(W0 + (67ull << 20));         // 23 MiB: S1,S3,S5
    unsigned short* R2   = (unsigned short*)(W0 + (90ull << 20));         // 7 MiB:  S2,S4,S6
    unsigned short* R3   = (unsigned short*)(W0 + (97ull << 20));         // 20 MiB: U2,U4,U6,S7,P4
    float* WT1 = (float*)(W0 + (117ull << 20));
    unsigned short* S1 = R1, *S3 = R1, *S5 = R1;
    unsigned short* S2 = R2, *S4 = R2, *S6 = R2;
    unsigned short* U2 = R3, *U4 = R3, *U6 = R3;
    unsigned short* S7 = R3;
    unsigned short* P4 = (unsigned short*)((char*)R3 + (2ull << 20));
    float* O = (float*)d_out;

    // L1: conv1 fp32 -> OUT; IF -> S1 (padded 34x34)
    transpose_w<<<dim3(1, 4), 256, 0, stream>>>(w1, WT1, 128, 27);
    conv1_c<<<dim3(1024, 1, 2), 320, 0, stream>>>(x, WT1, b1, OUT);
    halo_zero<<<dim3(132, 2), 256, 0, stream>>>(S1, 34, 34, 5120);
    if_ci<<<1024, 256, 0, stream>>>(OUT, S1, thr1, 128, 32, 32, 34, 34, 1, 262144);

    // L2
    split_w<<<64, 256, 0, stream>>>(w2, WH, WMID, WLO, 128, 128);
    conv_p<128, 128, 34, 34, 1><<<1280, 256, 81920, stream>>>(S1, WLO, WMID, WH, b2, OUT);
    if_ci<<<1024, 256, 0, stream>>>(OUT, U2, thr2, 128, 32, 32, 32, 32, 0, 262144);
    halo_zero<<<dim3(68, 2), 256, 0, stream>>>(S2, 18, 18, 5120);
    pool_ci<<<256, 256, 0, stream>>>(U2, S2, p1, 128, 16, 16, 32, 32, 0, 18, 18, 1, 65536);

    // L3
    split_w<<<128, 256, 0, stream>>>(w3, WH, WMID, WLO, 256, 128);
    conv_p<128, 256, 18, 18, 1><<<640, 256, 81920, stream>>>(S2, WLO, WMID, WH, b3, OUT);
    halo_zero<<<dim3(68, 2), 256, 0, stream>>>(S3, 18, 18, 10240);
    if_ci<<<512, 256, 0, stream>>>(OUT, S3, thr3, 256, 16, 16, 18, 18, 1, 131072);

    // L4
    split_w<<<256, 256, 0, stream>>>(w4, WH, WMID, WLO, 256, 256);
    conv_p<256, 256, 18, 18, 1><<<640, 256, 81920, stream>>>(S3, WLO, WMID, WH, b4, OUT);
    if_ci<<<512, 256, 0, stream>>>(OUT, U4, thr4, 256, 16, 16, 16, 16, 0, 131072);
    halo_zero<<<dim3(36, 2), 256, 0, stream>>>(S4, 10, 10, 10240);
    pool_ci<<<128, 256, 0, stream>>>(U4, S4, p2, 256, 8, 8, 16, 16, 0, 10, 10, 1, 32768);

    // L5
    split_w<<<512, 256, 0, stream>>>(w5, WH, WMID, WLO, 512, 256);
    conv_p<256, 512, 10, 10, 1><<<320, 256, 81920, stream>>>(S4, WLO, WMID, WH, b5, OUT);
    halo_zero<<<dim3(36, 2), 256, 0, stream>>>(S5, 10, 10, 20480);
    if_ci<<<256, 256, 0, stream>>>(OUT, S5, thr5, 512, 8, 8, 10, 10, 1, 65536);

    // L6
    split_w<<<1024, 256, 0, stream>>>(w6, WH, WMID, WLO, 512, 512);
    conv_p<512, 512, 10, 10, 1><<<320, 256, 81920, stream>>>(S5, WLO, WMID, WH, b6, OUT);
    if_ci<<<256, 256, 0, stream>>>(OUT, U6, thr6, 512, 8, 8, 8, 8, 0, 65536);
    pool_ci<<<64, 256, 0, stream>>>(U6, S6, p3, 512, 4, 4, 8, 8, 0, 4, 4, 0, 16384);

    // L7: K-split x4 -> slabs in OUT; reduce+IF -> S7 (dense 2x2)
    split_w<<<2048, 256, 0, stream>>>(w7, WH, WMID, WLO, 1024, 512);
    conv_p<128, 1024, 4, 4, 4><<<256, 256, 81920, stream>>>(S6, WLO, WMID, WH, b7, OUT);
    reduce_if7<<<32, 256, 0, stream>>>(OUT, S7, thr7, 8192);
    pool_ci<<<8, 256, 0, stream>>>(S7, P4, p4, 1024, 1, 1, 2, 2, 0, 1, 1, 0, 2048);

    // classifier
    classifier_ci<<<1, 1024, 0, stream>>>(P4, wc, bc, O);
}

// Round 6
// 623.602 us; speedup vs baseline: 3.1929x; 3.1929x over previous
//
#include <hip/hip_runtime.h>

// SNN forward, xs-path only. Spike layouts zero-halo padded (N,H+2,W+2,T,C), T=40.
// Convs 2-7: MFMA 16x16x32 bf16, EXACT 3-way bf16 weight split.
// conv_t14: BM=128 (2img x 64) x BN=64 x BK=64 tile, single 40KB LDS buffer,
// T14 reg-prefetch pipeline: ds_write(cur) ; issue global loads(next) ;
// lgkmcnt(0)+s_barrier (no vmcnt drain!) ; 192 MFMA ; s_barrier.

constexpr int NT = 40;

typedef __attribute__((ext_vector_type(8))) short s16x8;
typedef __attribute__((ext_vector_type(4))) float f32x4;

__device__ __forceinline__ float bf2f(unsigned short u) {
    return __uint_as_float(((unsigned)u) << 16);
}

__device__ __forceinline__ void wg_barrier() {
    __builtin_amdgcn_sched_barrier(0);
    __builtin_amdgcn_s_barrier();
    __builtin_amdgcn_sched_barrier(0);
}

// ---------------- weight transpose for conv1 ----------------
__global__ __launch_bounds__(256) void transpose_w(
    const float* __restrict__ w, float* __restrict__ wt, int CO, int R)
{
    __shared__ float tile[32][33];
    const int r0 = blockIdx.x * 32, c0 = blockIdx.y * 32;
    const int tx = threadIdx.x % 32, ty = threadIdx.x / 32;
#pragma unroll
    for (int k = 0; k < 4; k++) {
        const int co = c0 + ty + k * 8, r = r0 + tx;
        if (co < CO && r < R) tile[ty + k * 8][tx] = w[(size_t)co * R + r];
    }
    __syncthreads();
#pragma unroll
    for (int k = 0; k < 4; k++) {
        const int r = r0 + ty + k * 8, co = c0 + tx;
        if (r < R && co < CO) wt[(size_t)r * CO + co] = tile[tx][ty + k * 8];
    }
}

// ---------------- conv1: 3->128 @32x32 pad1, fp32 VALU, dense out ----------------
__global__ __launch_bounds__(320) void conv1_c(
    const float* __restrict__ in, const float* __restrict__ wt,
    const float* __restrict__ bias, float* __restrict__ out)
{
    __shared__ float xs_[27 * NT];
    __shared__ float wl[27 * 128];
    const int sp = blockIdx.x;
    const int ho = sp >> 5, wo = sp & 31;
    const int n = blockIdx.z;
    const int tid = threadIdx.x;
    const int tt = tid >> 5;
    const int cc = tid & 31;

    float4 acc[4];
#pragma unroll
    for (int j = 0; j < 4; j++) {
        const float bv = bias[cc * 4 + j];
        acc[j] = make_float4(bv, bv, bv, bv);
    }
    for (int u = tid; u < 270; u += 320) {
        const int r = u / 10, q = u % 10;
        const int cil = r / 9, k = r % 9;
        const int hi = ho + k / 3 - 1, wi = wo + k % 3 - 1;
        float4 v = make_float4(0.f, 0.f, 0.f, 0.f);
        if ((unsigned)hi < 32u && (unsigned)wi < 32u)
            v = *reinterpret_cast<const float4*>(
                in + ((size_t)((n * 3 + cil) * 1024 + hi * 32 + wi)) * NT + q * 4);
        *reinterpret_cast<float4*>(&xs_[r * NT + q * 4]) = v;
    }
    for (int u = tid; u < 864; u += 320) {
        const int r = u >> 5, j = u & 31;
        *reinterpret_cast<float4*>(&wl[r * 128 + j * 4]) =
            *reinterpret_cast<const float4*>(wt + r * 128 + j * 4);
    }
    __syncthreads();
#pragma unroll
    for (int r = 0; r < 27; ++r) {
        const float4 xv = *reinterpret_cast<const float4*>(&xs_[r * NT + tt * 4]);
        const float4 wv = *reinterpret_cast<const float4*>(&wl[r * 128 + cc * 4]);
        acc[0].x = fmaf(xv.x, wv.x, acc[0].x); acc[0].y = fmaf(xv.y, wv.x, acc[0].y);
        acc[0].z = fmaf(xv.z, wv.x, acc[0].z); acc[0].w = fmaf(xv.w, wv.x, acc[0].w);
        acc[1].x = fmaf(xv.x, wv.y, acc[1].x); acc[1].y = fmaf(xv.y, wv.y, acc[1].y);
        acc[1].z = fmaf(xv.z, wv.y, acc[1].z); acc[1].w = fmaf(xv.w, wv.y, acc[1].w);
        acc[2].x = fmaf(xv.x, wv.z, acc[2].x); acc[2].y = fmaf(xv.y, wv.z, acc[2].y);
        acc[2].z = fmaf(xv.z, wv.z, acc[2].z); acc[2].w = fmaf(xv.w, wv.z, acc[2].w);
        acc[3].x = fmaf(xv.x, wv.w, acc[3].x); acc[3].y = fmaf(xv.y, wv.w, acc[3].y);
        acc[3].z = fmaf(xv.z, wv.w, acc[3].z); acc[3].w = fmaf(xv.w, wv.w, acc[3].w);
    }
    const size_t base = (size_t)(n * 1024 + sp) * (NT * 128);
#pragma unroll
    for (int j = 0; j < 4; j++) {
        const int cb = cc * 4 + j;
        out[base + (tt * 4 + 0) * 128 + cb] = acc[j].x;
        out[base + (tt * 4 + 1) * 128 + cb] = acc[j].y;
        out[base + (tt * 4 + 2) * 128 + cb] = acc[j].z;
        out[base + (tt * 4 + 3) * 128 + cb] = acc[j].w;
    }
}

// ---------------- exact 3-way bf16 split: w[CO][CIN*9] -> {hi,mid,lo}[9][CO][CIN] ----------------
__global__ void split_w(const float* __restrict__ w,
                        unsigned short* __restrict__ hi, unsigned short* __restrict__ mid,
                        unsigned short* __restrict__ lo, int CO, int CIN_)
{
    const int idx = blockIdx.x * blockDim.x + threadIdx.x;
    if (idx >= CO * CIN_) return;
    const int co = idx / CIN_, ci = idx % CIN_;
    const float* src = w + ((size_t)co * CIN_ + ci) * 9;
#pragma unroll
    for (int k = 0; k < 9; ++k) {
        const float f = src[k];
        const unsigned u = __float_as_uint(f);
        const float fh = __uint_as_float(u & 0xFFFF0000u);
        const float r1 = f - fh;
        const unsigned u1 = __float_as_uint(r1);
        const float fm = __uint_as_float(u1 & 0xFFFF0000u);
        const float r2 = r1 - fm;
        const unsigned u2 = __float_as_uint(r2);
        const size_t dst = ((size_t)k * CO + co) * CIN_ + ci;
        hi[dst] = (unsigned short)(u >> 16);
        mid[dst] = (unsigned short)(u1 >> 16);
        lo[dst] = (unsigned short)(u2 >> 16);
    }
}

// ---------------- T14 reg-prefetch MFMA conv on padded spikes ----------------
template<int CIN_SEG, int COUT, int HP, int WP, int NSPLIT>
__global__ __launch_bounds__(256, 2) void conv_t14(
    const unsigned short* __restrict__ spk,
    const unsigned short* __restrict__ wlo, const unsigned short* __restrict__ wmid,
    const unsigned short* __restrict__ whi,
    const float* __restrict__ bias, float* __restrict__ out)
{
    constexpr int CIN = CIN_SEG * NSPLIT;
    constexpr int HO = HP - 2, WO = WP - 2;
    constexpr int MROW = WO * NT;
    constexpr int MTILES = (MROW + 63) / 64;
    constexpr int KC = CIN_SEG / 64;
    constexpr int NCHUNK = 9 * KC;
    static_assert(NCHUNK % 2 == 0, "chunk loop unrolled by 2");
    constexpr int NX = HO * MTILES;
    constexpr int NY = COUT / 64;
    constexpr int NB = NX * NSPLIT * NY;
    static_assert(NB % 8 == 0, "grid must divide across 8 XCDs");
    constexpr int Q = NB / 8;
    constexpr size_t SLAB = (size_t)2 * HO * WO * NT * COUT;

    __shared__ unsigned short smem[20480];   // A[128][64] + B[3][64][64] = 40 KiB

    // XCD-chunked swizzle: x fastest (shares B panel per XCD), then split, then y
    const int g = blockIdx.x;
    const int orig = (g & 7) * Q + (g >> 3);
    const int x = orig % NX;
    const int split = (orig / NX) % NSPLIT;
    const int y = orig / (NX * NSPLIT);
    const int ho = x / MTILES;
    const int m0 = (x % MTILES) * 64;
    const int co0 = y * 64;

    const int tid = threadIdx.x;
    const int lane = tid & 63;
    const int wv = tid >> 6;
    const int wm = wv >> 1, wn = wv & 1;
    const int lr = lane >> 4, lc = lane & 15;
    const int rlane = lane >> 3, blane = lane & 7;
    const int swz = ((blane ^ rlane) << 3);

    // per-slot constants (slot = wv*10 + s; 0-15: A img rows, 16-39: B 3 splits)
    int lofs[10]; int arow[10]; int gstat[10]; const unsigned short* wbase[10]; bool isA[10];
#pragma unroll
    for (int s = 0; s < 10; ++s) {
        const int slot = wv * 10 + s;
        if (slot < 16) {
            const int img = slot >> 3, r0 = (slot & 7) << 3;
            isA[s] = true;
            arow[s] = m0 + r0 + rlane;
            lofs[s] = (img * 64 + r0 + rlane) * 64 + swz;
            gstat[s] = (int)((img * HP * WP * NT + arow[s]) * CIN + blane * 8);
            wbase[s] = spk;
        } else {
            const int si = slot - 16;
            const int sp_ = si >> 3, r0 = (si & 7) << 3;
            isA[s] = false;
            arow[s] = 0;
            lofs[s] = 8192 + (sp_ * 64 + r0 + rlane) * 64 + swz;
            gstat[s] = (int)((co0 + r0 + rlane) * CIN + blane * 8);
            wbase[s] = (sp_ == 0) ? wlo : ((sp_ == 1) ? wmid : whi);
        }
    }

    f32x4 acc[2][2][2];
#pragma unroll
    for (int img = 0; img < 2; ++img)
#pragma unroll
        for (int mf = 0; mf < 2; ++mf)
#pragma unroll
            for (int nf = 0; nf < 2; ++nf) {
                const float bv = (NSPLIT == 1 || split == 0)
                    ? bias[co0 + wn * 32 + nf * 16 + lc] : 0.f;
                acc[img][mf][nf] = {bv, bv, bv, bv};
            }

    auto loadchunk = [&](s16x8 (&r)[10], int c) {
        const int kh = c / (3 * KC);
        const int rem = c - kh * 3 * KC;
        const int kw = rem / KC;
        const int kc = rem - kw * KC;
        const int khw = kh * 3 + kw;
        const int ci0 = split * CIN_SEG + kc * 64;
        const size_t aoff = ((size_t)(ho + kh) * WP * NT + (size_t)kw * NT) * CIN + ci0;
        const size_t boff = (size_t)khw * COUT * CIN + ci0;
#pragma unroll
        for (int s = 0; s < 10; ++s) {
            if (isA[s]) {
                s16x8 v = {0, 0, 0, 0, 0, 0, 0, 0};
                if (arow[s] < MROW)
                    v = *(const s16x8*)(spk + aoff + (size_t)gstat[s]);
                r[s] = v;
            } else {
                r[s] = *(const s16x8*)(wbase[s] + boff + (size_t)gstat[s]);
            }
        }
    };

    auto writechunk = [&](s16x8 (&r)[10]) {
#pragma unroll
        for (int s = 0; s < 10; ++s)
            *(s16x8*)&smem[lofs[s]] = r[s];
    };

    auto compute = [&]() {
#pragma unroll
        for (int kcs = 0; kcs < 2; ++kcs) {
            const int cswz = (((kcs * 4 + lr) ^ (lc & 7)) << 3);
            s16x8 af[2][2];
#pragma unroll
            for (int img = 0; img < 2; ++img)
#pragma unroll
                for (int mf = 0; mf < 2; ++mf)
                    af[img][mf] = *(const s16x8*)&smem[(img * 64 + wm * 32 + mf * 16 + lc) * 64 + cswz];
#pragma unroll
            for (int s = 0; s < 3; ++s)
#pragma unroll
                for (int nf = 0; nf < 2; ++nf) {
                    const s16x8 bq = *(const s16x8*)&smem[8192 + s * 4096 + (wn * 32 + nf * 16 + lc) * 64 + cswz];
#pragma unroll
                    for (int img = 0; img < 2; ++img)
#pragma unroll
                        for (int mf = 0; mf < 2; ++mf)
                            acc[img][mf][nf] = __builtin_amdgcn_mfma_f32_16x16x32_bf16(
                                af[img][mf], bq, acc[img][mf][nf], 0, 0, 0);
                }
        }
    };

    s16x8 ra[10], rb[10];
    loadchunk(ra, 0);
#pragma unroll 1
    for (int c = 0; c < NCHUNK; c += 2) {
        writechunk(ra);                 // compiler inserts vmcnt waits for ra here
        loadchunk(rb, c + 1);           // next chunk's globals in flight
        asm volatile("s_waitcnt lgkmcnt(0)" ::: "memory");
        wg_barrier();
        compute();                      // 192 MFMA/block, globals land underneath
        wg_barrier();
        writechunk(rb);
        if (c + 2 < NCHUNK) loadchunk(ra, c + 2);
        asm volatile("s_waitcnt lgkmcnt(0)" ::: "memory");
        wg_barrier();
        compute();
        wg_barrier();
    }

#pragma unroll
    for (int img = 0; img < 2; ++img) {
        float* outp = out + (size_t)split * SLAB + ((size_t)(img * HO + ho) * WO * NT) * COUT;
#pragma unroll
        for (int mf = 0; mf < 2; ++mf) {
            const int mbase = m0 + wm * 32 + mf * 16;
            if (mbase >= MROW) continue;
#pragma unroll
            for (int nf = 0; nf < 2; ++nf) {
                const int col = co0 + wn * 32 + nf * 16 + lc;
#pragma unroll
                for (int j = 0; j < 4; ++j) {
                    const int m = mbase + lr * 4 + j;
                    outp[(size_t)m * COUT + col] = acc[img][mf][nf][j];
                }
            }
        }
    }
}

// ---------------- zero the 1-cell halo ring of a padded spike buffer ----------------
__global__ void halo_zero(unsigned short* __restrict__ buf, int HP, int WP, int TC)
{
    const int cell = blockIdx.x, n = blockIdx.y;
    int h, w;
    if (cell < WP)            { h = 0;       w = cell; }
    else if (cell < 2 * WP)   { h = HP - 1;  w = cell - WP; }
    else { const int s = cell - 2 * WP; h = 1 + (s >> 1); w = (s & 1) ? (WP - 1) : 0; }
    unsigned short* p = buf + (((size_t)(n * HP + h) * WP) + w) * TC;
    const s16x8 z = {0, 0, 0, 0, 0, 0, 0, 0};
    for (int i = threadIdx.x * 8; i < TC; i += blockDim.x * 8)
        *(s16x8*)(p + i) = z;
}

// ---------------- IF scan: fp32 dense conv-out -> bf16 spikes (padded or not) ----------------
__global__ void if_ci(const float* __restrict__ in, unsigned short* __restrict__ spk,
                      const float* __restrict__ thr, int C, int HO, int WO,
                      int HP, int WP, int off, int total)
{
    const int idx = blockIdx.x * blockDim.x + threadIdx.x;
    if (idx >= total) return;
    const int c = idx % C;
    const int sp = idx / C;
    const int wo = sp % WO;
    const int ho = (sp / WO) % HO;
    const int n = sp / (WO * HO);
    const float th = thr[c];
    const size_t ib = (size_t)sp * NT * C + c;
    const size_t ob = (((size_t)(n * HP + ho + off) * WP) + wo + off) * NT * C + c;
    float v = 0.f;
#pragma unroll
    for (int t = 0; t < NT; ++t) {
        v += in[ib + (size_t)t * C];
        const float s = (v >= th) ? 1.f : 0.f;
        v -= s * th;
        spk[ob + (size_t)t * C] = (s != 0.f) ? (unsigned short)0x3F80 : (unsigned short)0;
    }
}

// ---------------- pool 2x2 + IF, bf16 spikes in (padded) -> out (padded or not) ----------------
__global__ void pool_ci(const unsigned short* __restrict__ in, unsigned short* __restrict__ out,
                        const float* __restrict__ thr, int C, int HO, int WO,
                        int IHP, int IWP, int offi, int OHP, int OWP, int offo, int total)
{
    const int idx = blockIdx.x * blockDim.x + threadIdx.x;
    if (idx >= total) return;
    const int c = idx % C;
    const int sp = idx / C;
    const int wo = sp % WO;
    const int ho = (sp / WO) % HO;
    const int n = sp / (WO * HO);
    const float th = thr[c];
    const size_t i00 = (((size_t)(n * IHP + 2 * ho + offi) * IWP) + 2 * wo + offi) * NT * C + c;
    const size_t dW = (size_t)NT * C, dH = (size_t)IWP * NT * C;
    const size_t ob = (((size_t)(n * OHP + ho + offo) * OWP) + wo + offo) * NT * C + c;
    float v = 0.f;
#pragma unroll
    for (int t = 0; t < NT; ++t) {
        const size_t o = (size_t)t * C;
        const float a = bf2f(in[i00 + o]) + bf2f(in[i00 + dW + o]) +
                        bf2f(in[i00 + dH + o]) + bf2f(in[i00 + dH + dW + o]);
        v += a * 0.25f;
        const float s = (v >= th) ? 1.f : 0.f;
        v -= s * th;
        out[ob + o] = (s != 0.f) ? (unsigned short)0x3F80 : (unsigned short)0;
    }
}

// ---------------- conv7 4-way partial reduce + IF -> bf16 spikes (dense) ----------------
__global__ void reduce_if7(const float* __restrict__ part, unsigned short* __restrict__ out,
                           const float* __restrict__ thr, int total)
{
    const int idx = blockIdx.x * blockDim.x + threadIdx.x;
    if (idx >= total) return;
    const int c = idx & 1023;
    const size_t base = (size_t)(idx >> 10) * NT * 1024 + c;
    const size_t SL = 327680;
    const float th = thr[c];
    float v = 0.f;
#pragma unroll
    for (int t = 0; t < NT; ++t) {
        const size_t o = (size_t)t * 1024;
        const float x = part[base + o] + part[SL + base + o] +
                        part[2 * SL + base + o] + part[3 * SL + base + o];
        v += x;
        const float s = (v >= th) ? 1.f : 0.f;
        v -= s * th;
        out[base + o] = (s != 0.f) ? (unsigned short)0x3F80 : (unsigned short)0;
    }
}

// ---------------- classifier: bf16 spikes (N,T,1024) ----------------
__global__ __launch_bounds__(1024) void classifier_ci(
    const unsigned short* __restrict__ s, const float* __restrict__ wc,
    const float* __restrict__ bc, float* __restrict__ out)
{
    __shared__ float cnt[2][1024];
    const int c = threadIdx.x;
    for (int n = 0; n < 2; n++) {
        float sum = 0.f;
#pragma unroll
        for (int t = 0; t < NT; ++t) sum += bf2f(s[(size_t)(n * NT + t) * 1024 + c]);
        cnt[n][c] = sum;
    }
    __syncthreads();
    if (threadIdx.x < 20) {
        const int n = threadIdx.x / 10, o = threadIdx.x % 10;
        float a = 0.f;
        for (int k = 0; k < 1024; k++) a += cnt[n][k] * wc[o * 1024 + k];
        out[n * 10 + o] = a * (1.f / 40.f) + bc[o];
    }
}

extern "C" void kernel_launch(void* const* d_in, const int* in_sizes, int n_in,
                              void* d_out, int out_size, void* d_ws, size_t ws_size,
                              hipStream_t stream)
{
    const float* x   = (const float*)d_in[0];
    const float* w1  = (const float*)d_in[1];  const float* b1 = (const float*)d_in[2];
    const float* w2  = (const float*)d_in[3];  const float* b2 = (const float*)d_in[4];
    const float* w3  = (const float*)d_in[5];  const float* b3 = (const float*)d_in[6];
    const float* w4  = (const float*)d_in[7];  const float* b4 = (const float*)d_in[8];
    const float* w5  = (const float*)d_in[9];  const float* b5 = (const float*)d_in[10];
    const float* w6  = (const float*)d_in[11]; const float* b6 = (const float*)d_in[12];
    const float* w7  = (const float*)d_in[13]; const float* b7 = (const float*)d_in[14];
    const float* wc  = (const float*)d_in[15]; const float* bc = (const float*)d_in[16];
    const float* thr1 = (const float*)d_in[17];
    const float* thr2 = (const float*)d_in[18];
    const float* p1   = (const float*)d_in[19];
    const float* thr3 = (const float*)d_in[20];
    const float* thr4 = (const float*)d_in[21];
    const float* p2   = (const float*)d_in[22];
    const float* thr5 = (const float*)d_in[23];
    const float* thr6 = (const float*)d_in[24];
    const float* p3   = (const float*)d_in[25];
    const float* thr7 = (const float*)d_in[26];
    const float* p4   = (const float*)d_in[27];

    char* W0 = (char*)d_ws;
    float* OUT = (float*)W0;                                              // 40 MiB dense fp32
    unsigned short* WH   = (unsigned short*)(W0 + (40ull << 20));         // 9 MiB
    unsigned short* WMID = (unsigned short*)(W0 + (49ull << 20));         // 9 MiB
    unsigned short* WLO  = (unsigned short*)(W0 + (58ull << 20));         // 9 MiB
    unsigned short* R1   = (unsigned short*)(W0 + (67ull << 20));         // 23 MiB: S1,S3,S5
    unsigned short* R2   = (unsigned short*)(W0 + (90ull << 20));         // 7 MiB:  S2,S4,S6
    unsigned short* R3   = (unsigned short*)(W0 + (97ull << 20));         // 20 MiB: U2,U4,U6,S7,P4
    float* WT1 = (float*)(W0 + (117ull << 20));
    unsigned short* S1 = R1, *S3 = R1, *S5 = R1;
    unsigned short* S2 = R2, *S4 = R2, *S6 = R2;
    unsigned short* U2 = R3, *U4 = R3, *U6 = R3;
    unsigned short* S7 = R3;
    unsigned short* P4 = (unsigned short*)((char*)R3 + (2ull << 20));
    float* O = (float*)d_out;

    // L1: conv1 fp32 -> OUT; IF -> S1 (padded 34x34)
    transpose_w<<<dim3(1, 4), 256, 0, stream>>>(w1, WT1, 128, 27);
    conv1_c<<<dim3(1024, 1, 2), 320, 0, stream>>>(x, WT1, b1, OUT);
    halo_zero<<<dim3(132, 2), 256, 0, stream>>>(S1, 34, 34, 5120);
    if_ci<<<1024, 256, 0, stream>>>(OUT, S1, thr1, 128, 32, 32, 34, 34, 1, 262144);

    // L2: NX=32*20=640, NY=2 -> 1280 blocks
    split_w<<<64, 256, 0, stream>>>(w2, WH, WMID, WLO, 128, 128);
    conv_t14<128, 128, 34, 34, 1><<<1280, 256, 0, stream>>>(S1, WLO, WMID, WH, b2, OUT);
    if_ci<<<1024, 256, 0, stream>>>(OUT, U2, thr2, 128, 32, 32, 32, 32, 0, 262144);
    halo_zero<<<dim3(68, 2), 256, 0, stream>>>(S2, 18, 18, 5120);
    pool_ci<<<256, 256, 0, stream>>>(U2, S2, p1, 128, 16, 16, 32, 32, 0, 18, 18, 1, 65536);

    // L3: NX=16*10=160, NY=4 -> 640 blocks
    split_w<<<128, 256, 0, stream>>>(w3, WH, WMID, WLO, 256, 128);
    conv_t14<128, 256, 18, 18, 1><<<640, 256, 0, stream>>>(S2, WLO, WMID, WH, b3, OUT);
    halo_zero<<<dim3(68, 2), 256, 0, stream>>>(S3, 18, 18, 10240);
    if_ci<<<512, 256, 0, stream>>>(OUT, S3, thr3, 256, 16, 16, 18, 18, 1, 131072);

    // L4: 640 blocks
    split_w<<<256, 256, 0, stream>>>(w4, WH, WMID, WLO, 256, 256);
    conv_t14<256, 256, 18, 18, 1><<<640, 256, 0, stream>>>(S3, WLO, WMID, WH, b4, OUT);
    if_ci<<<512, 256, 0, stream>>>(OUT, U4, thr4, 256, 16, 16, 16, 16, 0, 131072);
    halo_zero<<<dim3(36, 2), 256, 0, stream>>>(S4, 10, 10, 10240);
    pool_ci<<<128, 256, 0, stream>>>(U4, S4, p2, 256, 8, 8, 16, 16, 0, 10, 10, 1, 32768);

    // L5: NX=8*5=40, NY=8 -> 320 blocks
    split_w<<<512, 256, 0, stream>>>(w5, WH, WMID, WLO, 512, 256);
    conv_t14<256, 512, 10, 10, 1><<<320, 256, 0, stream>>>(S4, WLO, WMID, WH, b5, OUT);
    halo_zero<<<dim3(36, 2), 256, 0, stream>>>(S5, 10, 10, 20480);
    if_ci<<<256, 256, 0, stream>>>(OUT, S5, thr5, 512, 8, 8, 10, 10, 1, 65536);

    // L6: 320 blocks
    split_w<<<1024, 256, 0, stream>>>(w6, WH, WMID, WLO, 512, 512);
    conv_t14<512, 512, 10, 10, 1><<<320, 256, 0, stream>>>(S5, WLO, WMID, WH, b6, OUT);
    if_ci<<<256, 256, 0, stream>>>(OUT, U6, thr6, 512, 8, 8, 8, 8, 0, 65536);
    pool_ci<<<64, 256, 0, stream>>>(U6, S6, p3, 512, 4, 4, 8, 8, 0, 4, 4, 0, 16384);

    // L7: K-split x4, dense 4x4 input; NX=2*2=4, NY=16, NSPLIT=4 -> 256 blocks
    split_w<<<2048, 256, 0, stream>>>(w7, WH, WMID, WLO, 1024, 512);
    conv_t14<128, 1024, 4, 4, 4><<<256, 256, 0, stream>>>(S6, WLO, WMID, WH, b7, OUT);
    reduce_if7<<<32, 256, 0, stream>>>(OUT, S7, thr7, 8192);
    pool_ci<<<8, 256, 0, stream>>>(S7, P4, p4, 1024, 1, 1, 2, 2, 0, 1, 1, 0, 2048);

    // classifier
    classifier_ci<<<1, 1024, 0, stream>>>(P4, wc, bc, O);
}